// Round 11
// baseline (21.107 us; speedup 1.0000x reference)
//
#include <hip/hip_runtime.h>
#include <math.h>

#define NPTS 4096
#define NB   8
#define QCB  512          // queries per block (16 waves x 32 rows)
#define RCB  512          // refs per block (16 tiles x 32)
#define NQC  (NPTS / QCB) // 8
#define NRC  (NPTS / RCB) // 8
#define NRT  (RCB / 32)   // 16 ref tiles per block

typedef _Float16 h8     __attribute__((ext_vector_type(8)));
typedef float    f32x16 __attribute__((ext_vector_type(16)));

__device__ __forceinline__ void split2(float v, _Float16& h, _Float16& l) {
    h = (_Float16)v;
    l = (_Float16)(v - (float)h);
}

// d = pn + gn - 2 p.g embedded in a K=16 f16 dot product via hi/lo split
// (hh + lo_a*hi_b + hi_a*lo_b products; fp32-exact to ~1e-6, validated R9/R10).
// Inner loop: 1 ds_read_b128 + 1 MFMA + ~31 fmin + 1 ds_write_b32.
// No LDS atomics: per-(wave,kg) col-mins go to a private rcol slice,
// combined by a post-loop drain phase (plain conflict-free reads).
__global__ __launch_bounds__(1024, 2) void chamfer_mfma32(
    const float* __restrict__ P, const float* __restrict__ G,
    float* __restrict__ qpart,   // [NB][NRC][NPTS] per-point min over ref-chunk
    float* __restrict__ rpart,   // [NB][NQC][NPTS] per-gt min over query-chunk
    int* __restrict__ counter)
{
    __shared__ __align__(16) unsigned char smem[81920];   // exactly 80 KB
    h8*    Bfr  = (h8*)smem;                   // [0, 16384): 16 tiles x 64 entries
    float* rcol = (float*)(smem + 16384);      // [16384, 81920): 32 groups x 512
    float* qbufall = (float*)smem;             // aliased in phase 3 only

    const int b    = blockIdx.y;
    const int qc   = blockIdx.x >> 3;   // 0..7
    const int rc   = blockIdx.x & 7;    // 0..7
    const int tid  = threadIdx.x;
    const int w    = tid >> 6;
    const int lane = tid & 63;
    const int col  = lane & 31;
    const int kg   = lane >> 5;

    if (blockIdx.x == 0 && blockIdx.y == 0 && tid == 0) *counter = 0;

    const float* __restrict__ Pb = P + (size_t)b * NPTS * 3;
    const float* __restrict__ Gb = G + (size_t)b * NPTS * 3;

    const _Float16 one = (_Float16)1.f, zr = (_Float16)0.f;

    // ---- phase 0: stage B-frags (1024 entries, 1 per thread)
    {
        const int e    = tid;
        const int el   = e & 63;
        const int ecol = el & 31, ekg = el >> 5;
        const int ref  = rc * RCB + (e >> 6) * 32 + ecol;
        const float gx = Gb[3 * ref], gy = Gb[3 * ref + 1], gz = Gb[3 * ref + 2];
        const float gn = fmaf(gx, gx, fmaf(gy, gy, gz * gz));
        _Float16 xh, xl, yh, yl, zh, zl, nh, nl;
        split2(gx, xh, xl); split2(gy, yh, yl); split2(gz, zh, zl); split2(gn, nh, nl);
        Bfr[e] = ekg ? (h8){one, nh, xl, yl, zl, zr, nl, zr}
                     : (h8){xh, yh, zh, one, nh, xh, yh, zh};
    }

    // ---- A-frag (per lane, registers)
    const int q0 = qc * QCB + w * 32 + col;
    const float px = Pb[3 * q0], py = Pb[3 * q0 + 1], pz = Pb[3 * q0 + 2];
    const float m2x = -2.f * px, m2y = -2.f * py, m2z = -2.f * pz;
    const float pn = fmaf(px, px, fmaf(py, py, pz * pz));
    _Float16 axh, axl, ayh, ayl, azh, azl, aph, apl;
    split2(m2x, axh, axl); split2(m2y, ayh, ayl); split2(m2z, azh, azl); split2(pn, aph, apl);
    const h8 afr = kg ? (h8){apl, zr, axh, ayh, azh, aph, one, zr}
                      : (h8){axh, ayh, azh, aph, one, axl, ayl, azl};

    f32x16 qacc;
#pragma unroll
    for (int j = 0; j < 16; ++j) qacc[j] = 3.4e38f;

    float* myrcol = rcol + (size_t)(w * 2 + kg) * 512 + col;

    __syncthreads();

    // ---- phase 1: NRT MFMAs; row-min into qacc regs, col-min -> private rcol
    const f32x16 cz = (f32x16){0.f,0.f,0.f,0.f,0.f,0.f,0.f,0.f,
                               0.f,0.f,0.f,0.f,0.f,0.f,0.f,0.f};
#pragma unroll
    for (int rt = 0; rt < NRT; ++rt) {
        const h8 bfr = Bfr[rt * 64 + lane];
        f32x16 d = __builtin_amdgcn_mfma_f32_32x32x16_f16(afr, bfr, cz, 0, 0, 0);
        float t0 = fminf(fminf(d[0],  d[1]),  d[2]);
        float t1 = fminf(fminf(d[3],  d[4]),  d[5]);
        float t2 = fminf(fminf(d[6],  d[7]),  d[8]);
        float t3 = fminf(fminf(d[9],  d[10]), d[11]);
        float t4 = fminf(fminf(d[12], d[13]), d[14]);
        myrcol[rt * 32] = fminf(fminf(fminf(t0, t1), t2), fminf(fminf(t3, t4), d[15]));
#pragma unroll
        for (int j = 0; j < 16; ++j) qacc[j] = fminf(qacc[j], d[j]);
    }

    // ---- phase 2: drain rcol (32 groups) -> rpart
    __syncthreads();
    if (tid < RCB) {
        float m0 = rcol[tid],        m1 = rcol[512 + tid];
        float m2 = rcol[1024 + tid], m3 = rcol[1536 + tid];
#pragma unroll
        for (int g = 4; g < 32; g += 4) {
            m0 = fminf(m0, rcol[(size_t)g * 512 + tid]);
            m1 = fminf(m1, rcol[(size_t)(g + 1) * 512 + tid]);
            m2 = fminf(m2, rcol[(size_t)(g + 2) * 512 + tid]);
            m3 = fminf(m3, rcol[(size_t)(g + 3) * 512 + tid]);
        }
        const float v = fminf(fminf(m0, m1), fminf(m2, m3));
        rpart[((size_t)b * NQC + qc) * NPTS + rc * RCB + tid] = fmaxf(v, 0.f);
    }
    __syncthreads();   // Bfr + rcol dead; qbuf may alias

    // ---- phase 3: qacc row-min via padded LDS transpose (per-wave region)
    float* qw = qbufall + w * 1152;            // 32 rows x 36 floats
#pragma unroll
    for (int j = 0; j < 16; ++j) {
        const int row = (j & 3) + 8 * (j >> 2) + 4 * kg;
        qw[row * 36 + col] = qacc[j];
    }
    __syncthreads();
    if (lane < 32) {
        const float4* qr = (const float4*)(qw + col * 36);
        float4 v = qr[0];
#pragma unroll
        for (int k = 1; k < 8; ++k) {
            float4 u = qr[k];
            v.x = fminf(v.x, u.x); v.y = fminf(v.y, u.y);
            v.z = fminf(v.z, u.z); v.w = fminf(v.w, u.w);
        }
        const float rowmin = fminf(fminf(v.x, v.y), fminf(v.z, v.w));
        qpart[((size_t)b * NRC + rc) * NPTS + qc * QCB + w * 32 + col] = rowmin;
    }
}

// Stage 2 (+fused finalize): 64 blocks; block = (path, b, sp of 4).
// Min-combine the 8 chunk partials per element, clamp, block-sum -> sums[64].
// Last block (atomic counter) combines 64 sums -> 16 sqrt(mean) -> 3 outputs.
__global__ __launch_bounds__(256) void chamfer_reduce2(
    const float* __restrict__ qpart, const float* __restrict__ rpart,
    float* __restrict__ sums, int* __restrict__ counter,
    float* __restrict__ out)
{
    const int path = blockIdx.x >> 5;          // 0..1
    const int b    = (blockIdx.x >> 2) & 7;    // 0..7
    const int sp   = blockIdx.x & 3;           // 0..3
    const float* __restrict__ base = (path ? rpart : qpart) + (size_t)b * 8 * NPTS;

    float sum = 0.f;
#pragma unroll
    for (int i = 0; i < 4; ++i) {
        const int q = sp * 1024 + i * 256 + threadIdx.x;
        float mn = base[q];
#pragma unroll
        for (int c = 1; c < 8; ++c) mn = fminf(mn, base[(size_t)c * NPTS + q]);
        sum += fmaxf(mn, 0.f);
    }

    __shared__ float red[256];
    __shared__ int amLast;
    red[threadIdx.x] = sum;
    __syncthreads();
    if (threadIdx.x < 128) red[threadIdx.x] += red[threadIdx.x + 128];
    __syncthreads();
    if (threadIdx.x < 64) {
        float v = red[threadIdx.x] + red[threadIdx.x + 64];
#pragma unroll
        for (int off = 32; off > 0; off >>= 1) v += __shfl_down(v, off, 64);
        if (threadIdx.x == 0) {
            sums[blockIdx.x] = v;
            __threadfence();
            amLast = (atomicAdd(counter, 1) == 63);
        }
    }
    __syncthreads();

    if (amLast) {
        __shared__ float r16[16];
        if (threadIdx.x < 16) {
            float s = 0.f;
#pragma unroll
            for (int k = 0; k < 4; ++k)
                s += *(volatile const float*)&sums[threadIdx.x * 4 + k];
            r16[threadIdx.x] = sqrtf(s / (float)NPTS);
        }
        __syncthreads();
        if (threadIdx.x == 0) {
            float p2g = 0.f, g2p = 0.f;
#pragma unroll
            for (int bb = 0; bb < NB; ++bb) { p2g += r16[bb]; g2p += r16[NB + bb]; }
            p2g *= (1.0f / NB);
            g2p *= (1.0f / NB);
            out[0] = 0.5f * (p2g + g2p);
            out[1] = p2g;
            out[2] = g2p;
            *counter = 0;   // leave clean for next replay
        }
    }
}

extern "C" void kernel_launch(void* const* d_in, const int* in_sizes, int n_in,
                              void* d_out, int out_size, void* d_ws, size_t ws_size,
                              hipStream_t stream) {
    const float* points = (const float*)d_in[0];
    const float* gts    = (const float*)d_in[1];
    float* out = (float*)d_out;

    float* qpart = (float*)d_ws;                          // 8*8*4096 = 1 MB
    float* rpart = qpart + (size_t)NB * NRC * NPTS;       // 8*8*4096 = 1 MB
    float* sums  = rpart + (size_t)NB * NQC * NPTS;       // 64 floats
    int*   counter = (int*)(sums + 64);

    dim3 grid1(NQC * NRC, NB);   // 64 x 8 = 512 blocks, 1024 thr, 2/CU
    chamfer_mfma32<<<grid1, 1024, 0, stream>>>(points, gts, qpart, rpart, counter);

    chamfer_reduce2<<<dim3(64), 256, 0, stream>>>(qpart, rpart, sums, counter, out);
}